// Round 4
// baseline (1433.520 us; speedup 1.0000x reference)
//
#include <hip/hip_runtime.h>
#include <math.h>

#define N_NODES 100000
#define N_EDGES 1600000
#define F_IN    16
#define H_DIM   32
#define B_GRAPHS 256

#define BSHIFT  7
#define BSIZE   128                                   // nodes per bucket
#define NBUCKET ((N_NODES + BSIZE - 1) / BSIZE)       // 782
#define EPB     8192                                  // edges per chunk block
#define NCHUNK  ((N_EDGES + EPB - 1) / EPB)           // 196

// ---------------------------------------------------------------------------
// bf16x2 helpers
__device__ inline float bf_lo(unsigned u) { return __uint_as_float(u << 16); }
__device__ inline float bf_hi(unsigned u) { return __uint_as_float(u & 0xffff0000u); }
__device__ inline unsigned pack_bf16x2(float a, float b) {
    unsigned ua = __float_as_uint(a), ub = __float_as_uint(b);
    ua += 0x7fffu + ((ua >> 16) & 1u);    // RNE
    ub += 0x7fffu + ((ub >> 16) & 1u);
    return (ua >> 16) | (ub & 0xffff0000u);
}

// ---------------------------------------------------------------------------
// Pass A: per-bucket edge histogram (bucket_cnt pre-zeroed)
__global__ __launch_bounds__(256) void passA_kernel(const int* __restrict__ dst,
                                                    int* __restrict__ bucket_cnt) {
    __shared__ int hist[NBUCKET];
    int t = threadIdx.x;
    for (int k = t; k < NBUCKET; k += 256) hist[k] = 0;
    __syncthreads();
    int base = blockIdx.x * EPB;
    int end  = base + EPB; if (end > N_EDGES) end = N_EDGES;
    for (int e = base + t; e < end; e += 256) atomicAdd(&hist[dst[e] >> BSHIFT], 1);
    __syncthreads();
    for (int k = t; k < NBUCKET; k += 256)
        if (hist[k]) atomicAdd(&bucket_cnt[k], hist[k]);
}

// Scan bucket counts -> bucket_off (exclusive, +sentinel) and bucket_cur copy.
__global__ __launch_bounds__(256) void scan_kernel(const int* __restrict__ bucket_cnt,
                                                   int* __restrict__ bucket_off,
                                                   int* __restrict__ bucket_cur) {
    __shared__ int s[1024];
    int t = threadIdx.x;
    int v[4];
    for (int r = 0; r < 4; ++r) {
        int k = t + 256 * r;
        int x = (k < NBUCKET) ? bucket_cnt[k] : 0;
        v[r] = x; s[k] = x;
    }
    __syncthreads();
    for (int off = 1; off < 1024; off <<= 1) {
        int tmp[4];
        for (int r = 0; r < 4; ++r) { int k = t + 256 * r; tmp[r] = (k >= off) ? s[k - off] : 0; }
        __syncthreads();
        for (int r = 0; r < 4; ++r) { int k = t + 256 * r; s[k] += tmp[r]; }
        __syncthreads();
    }
    for (int r = 0; r < 4; ++r) {
        int k = t + 256 * r;
        if (k < NBUCKET) {
            int excl = s[k] - v[r];
            bucket_off[k] = excl;
            bucket_cur[k] = excl;
        }
    }
    if (t == 0) bucket_off[NBUCKET] = s[1023];   // == N_EDGES
}

// Pass B: partition edges into bucket-major order, LDS-staged for locality.
// Record = src (bits 0..19) | dst_local (bits 20..26).
__global__ __launch_bounds__(256) void passB_kernel(const int* __restrict__ ei,
                                                    int* __restrict__ bucket_cur,
                                                    unsigned* __restrict__ rec_out) {
    __shared__ int hist[NBUCKET];
    __shared__ int sbase[NBUCKET];
    __shared__ int gbase[NBUCKET];
    __shared__ int scnt[NBUCKET];
    __shared__ int ssc[1024];
    __shared__ unsigned stage[EPB];
    int t = threadIdx.x;
    for (int k = t; k < NBUCKET; k += 256) { hist[k] = 0; scnt[k] = 0; }
    __syncthreads();

    const int* dst = ei + N_EDGES;
    int base = blockIdx.x * EPB;
    int end  = base + EPB; if (end > N_EDGES) end = N_EDGES;
    int n = end - base;

    for (int e = base + t; e < end; e += 256) atomicAdd(&hist[dst[e] >> BSHIFT], 1);
    __syncthreads();

    // exclusive scan of hist -> sbase
    int v[4];
    for (int r = 0; r < 4; ++r) {
        int k = t + 256 * r;
        int x = (k < NBUCKET) ? hist[k] : 0;
        v[r] = x; ssc[k] = x;
    }
    __syncthreads();
    for (int off = 1; off < 1024; off <<= 1) {
        int tmp[4];
        for (int r = 0; r < 4; ++r) { int k = t + 256 * r; tmp[r] = (k >= off) ? ssc[k - off] : 0; }
        __syncthreads();
        for (int r = 0; r < 4; ++r) { int k = t + 256 * r; ssc[k] += tmp[r]; }
        __syncthreads();
    }
    for (int r = 0; r < 4; ++r) {
        int k = t + 256 * r;
        if (k < NBUCKET) sbase[k] = ssc[k] - v[r];
    }
    // claim global per-bucket segments
    for (int k = t; k < NBUCKET; k += 256) {
        int h = hist[k];
        gbase[k] = h ? atomicAdd(&bucket_cur[k], h) : 0;
    }
    __syncthreads();

    // stage records bucket-major in LDS
    for (int e = base + t; e < end; e += 256) {
        int d = dst[e], s = ei[e];
        int bk = d >> BSHIFT;
        int off = atomicAdd(&scnt[bk], 1);
        stage[sbase[bk] + off] = (unsigned)s | ((unsigned)(d & (BSIZE - 1)) << 20);
    }
    __syncthreads();

    // stream out: slot k belongs to rightmost bucket with sbase[b] <= k
    for (int k = t; k < n; k += 256) {
        int lo = 0, hi = NBUCKET - 1;
        while (lo < hi) { int mid = (lo + hi + 1) >> 1; if (sbase[mid] <= k) lo = mid; else hi = mid - 1; }
        rec_out[gbase[lo] + (k - sbase[lo])] = stage[k];
    }
}

// Per-bucket in-degree -> dinv
__global__ __launch_bounds__(256) void dinv_kernel(const unsigned* __restrict__ rec,
                                                   const int* __restrict__ bucket_off,
                                                   float* __restrict__ dinv) {
    __shared__ int cnt[BSIZE];
    int t = threadIdx.x, b = blockIdx.x;
    if (t < BSIZE) cnt[t] = 0;
    __syncthreads();
    int e1 = bucket_off[b + 1];
    for (int e = bucket_off[b] + t; e < e1; e += 256) atomicAdd(&cnt[rec[e] >> 20], 1);
    __syncthreads();
    int nd = (b << BSHIFT) + t;
    if (t < BSIZE && nd < N_NODES) dinv[nd] = rsqrtf((float)cnt[t] + 1.0f);
}

// ---------------------------------------------------------------------------
// GCN layer, one block per bucket: LDS f32 aggregation (edge-parallel ds_add),
// then self-loop + W transform + bias + tanh + bf16x2 pack.
template <int FIN, bool PACKED>
__global__ __launch_bounds__(256) void layer_kernel(
        const void* __restrict__ h_in_v,
        const unsigned* __restrict__ rec,
        const int* __restrict__ bucket_off,
        const float* __restrict__ dinv,
        const float* __restrict__ W,       // [FIN][32]
        const float* __restrict__ bias,    // [32]
        unsigned* __restrict__ h_out) {
    constexpr int STR = FIN + 1;
    __shared__ float agg[BSIZE * STR];
    __shared__ float sW[FIN * H_DIM];
    __shared__ float sb[H_DIM];
    __shared__ float sdv[BSIZE];
    int t = threadIdx.x;
    int b = blockIdx.x;
    int node0 = b << BSHIFT;

    for (int k = t; k < FIN * H_DIM; k += 256) sW[k] = W[k];
    if (t < H_DIM) sb[t] = bias[t];
    if (t < BSIZE) {
        int nd = node0 + t;
        sdv[t] = (nd < N_NODES) ? dinv[nd] : 0.f;
    }
    for (int k = t; k < BSIZE * STR; k += 256) agg[k] = 0.f;
    __syncthreads();

    int e1 = bucket_off[b + 1];
    for (int e = bucket_off[b] + t; e < e1; e += 256) {
        unsigned r = rec[e];
        int s  = r & 0xFFFFF;
        int dl = r >> 20;
        float c = dinv[s] * sdv[dl];
        float* a = &agg[dl * STR];
        if (PACKED) {
            const uint4* row = (const uint4*)((const unsigned*)h_in_v + s * 16);
            uint4 q0 = row[0], q1 = row[1], q2 = row[2], q3 = row[3];
            unsigned q[16] = {q0.x, q0.y, q0.z, q0.w, q1.x, q1.y, q1.z, q1.w,
                              q2.x, q2.y, q2.z, q2.w, q3.x, q3.y, q3.z, q3.w};
#pragma unroll
            for (int u = 0; u < 16; ++u) {
                atomicAdd(&a[2 * u],     bf_lo(q[u]) * c);
                atomicAdd(&a[2 * u + 1], bf_hi(q[u]) * c);
            }
        } else {
            const float4* row = (const float4*)((const float*)h_in_v + s * F_IN);
            float4 f0 = row[0], f1 = row[1], f2 = row[2], f3 = row[3];
            atomicAdd(&a[0],  f0.x * c); atomicAdd(&a[1],  f0.y * c);
            atomicAdd(&a[2],  f0.z * c); atomicAdd(&a[3],  f0.w * c);
            atomicAdd(&a[4],  f1.x * c); atomicAdd(&a[5],  f1.y * c);
            atomicAdd(&a[6],  f1.z * c); atomicAdd(&a[7],  f1.w * c);
            atomicAdd(&a[8],  f2.x * c); atomicAdd(&a[9],  f2.y * c);
            atomicAdd(&a[10], f2.z * c); atomicAdd(&a[11], f2.w * c);
            atomicAdd(&a[12], f3.x * c); atomicAdd(&a[13], f3.y * c);
            atomicAdd(&a[14], f3.z * c); atomicAdd(&a[15], f3.w * c);
        }
    }
    __syncthreads();

    // self-loop term (disjoint, non-atomic)
    if (PACKED) {
        for (int idx = t; idx < BSIZE * 16; idx += 256) {
            int nl = idx >> 4, u = idx & 15;
            int nd = node0 + nl;
            if (nd < N_NODES) {
                unsigned q = ((const unsigned*)h_in_v)[nd * 16 + u];
                float d2 = sdv[nl] * sdv[nl];
                agg[nl * STR + 2 * u]     += bf_lo(q) * d2;
                agg[nl * STR + 2 * u + 1] += bf_hi(q) * d2;
            }
        }
    } else {
        for (int idx = t; idx < BSIZE * F_IN; idx += 256) {
            int nl = idx >> 4, k = idx & 15;
            int nd = node0 + nl;
            if (nd < N_NODES) {
                float d2 = sdv[nl] * sdv[nl];
                agg[nl * STR + k] += ((const float*)h_in_v)[nd * F_IN + k] * d2;
            }
        }
    }
    __syncthreads();

    // transform + bias + tanh + pack
    for (int idx = t; idx < BSIZE * 16; idx += 256) {
        int nl = idx >> 4, u = idx & 15;
        int nd = node0 + nl;
        if (nd >= N_NODES) continue;
        int j0 = 2 * u;
        float o0 = sb[j0], o1 = sb[j0 + 1];
        const float* arow = &agg[nl * STR];
#pragma unroll
        for (int k = 0; k < FIN; ++k) {
            float a = arow[k];
            o0 += a * sW[k * H_DIM + j0];
            o1 += a * sW[k * H_DIM + j0 + 1];
        }
        h_out[nd * 16 + u] = pack_bf16x2(tanhf(o0), tanhf(o1));
    }
}

// ---------------------------------------------------------------------------
// Per-graph pooling (batch sorted) + linear head, reading packed bf16 h.
__global__ __launch_bounds__(256) void pool_kernel(const unsigned* __restrict__ hp,
                                                   const int* __restrict__ batch,
                                                   const float* __restrict__ Wout,
                                                   const float* __restrict__ bout,
                                                   float* __restrict__ out) {
    int b = blockIdx.x;
    int t = threadIdx.x;
    int lane_n = t >> 5;
    int j = t & 31;

    int lo = 0, hi = N_NODES;
    while (lo < hi) { int mid = (lo + hi) >> 1; if (batch[mid] < b) lo = mid + 1; else hi = mid; }
    int start = lo;
    hi = N_NODES;
    while (lo < hi) { int mid = (lo + hi) >> 1; if (batch[mid] < b + 1) lo = mid + 1; else hi = mid; }
    int end = lo;

    float vmax = -INFINITY, vsum = 0.f;
    for (int i = start + lane_n; i < end; i += 8) {
        unsigned q = hp[i * 16 + (j >> 1)];
        float v = (j & 1) ? bf_hi(q) : bf_lo(q);
        vmax = fmaxf(vmax, v);
        vsum += v;
    }

    __shared__ float smax[8][32];
    __shared__ float ssum[8][32];
    __shared__ float pool96[96];
    smax[lane_n][j] = vmax;
    ssum[lane_n][j] = vsum;
    __syncthreads();

    if (t < 32) {
        float m = smax[0][t], s = ssum[0][t];
#pragma unroll
        for (int n = 1; n < 8; ++n) { m = fmaxf(m, smax[n][t]); s += ssum[n][t]; }
        int cnt = end - start;
        float mean = s / fmaxf((float)cnt, 1.0f);
        pool96[t]      = m;
        pool96[32 + t] = mean;
        pool96[64 + t] = s;
    }
    __syncthreads();

    if (t < 96) out[B_GRAPHS + b * 96 + t] = pool96[t];

    __shared__ float dotbuf[96];
    if (t < 96) dotbuf[t] = pool96[t] * Wout[t];
    __syncthreads();
    if (t == 0) {
        float acc = 0.f;
#pragma unroll
        for (int k = 0; k < 96; ++k) acc += dotbuf[k];
        out[b] = acc + bout[0];
    }
}

// ---------------------------------------------------------------------------
extern "C" void kernel_launch(void* const* d_in, const int* in_sizes, int n_in,
                              void* d_out, int out_size, void* d_ws, size_t ws_size,
                              hipStream_t stream) {
    const float* x     = (const float*)d_in[0];
    const int*   ei    = (const int*)  d_in[1];   // src = ei[0:E], dst = ei[E:2E]
    const int*   batch = (const int*)  d_in[2];
    const float* W0    = (const float*)d_in[3];
    const float* b0    = (const float*)d_in[4];
    const float* W1    = (const float*)d_in[5];
    const float* b1    = (const float*)d_in[6];
    const float* W2    = (const float*)d_in[7];
    const float* b2    = (const float*)d_in[8];
    const float* W3    = (const float*)d_in[9];
    const float* b3    = (const float*)d_in[10];
    const float* Wout  = (const float*)d_in[11];
    const float* bout  = (const float*)d_in[12];
    float* out = (float*)d_out;

    // workspace (16B-aligned chunks first)
    char* p = (char*)d_ws;
    float*    dinv       = (float*)p;    p += (size_t)N_NODES * 4;        // 400000
    unsigned* hA         = (unsigned*)p; p += (size_t)N_NODES * 16 * 4;   // 6.4 MB
    unsigned* hB         = (unsigned*)p; p += (size_t)N_NODES * 16 * 4;
    unsigned* rec        = (unsigned*)p; p += (size_t)N_EDGES * 4;        // 6.4 MB
    int*      bucket_cnt = (int*)p;      p += NBUCKET * 4;
    int*      bucket_off = (int*)p;      p += (NBUCKET + 1) * 4;
    int*      bucket_cur = (int*)p;      p += NBUCKET * 4;

    // ---- bucket-partitioned edge build ----
    hipMemsetAsync(bucket_cnt, 0, NBUCKET * sizeof(int), stream);
    passA_kernel<<<NCHUNK, 256, 0, stream>>>(ei + N_EDGES, bucket_cnt);
    scan_kernel<<<1, 256, 0, stream>>>(bucket_cnt, bucket_off, bucket_cur);
    passB_kernel<<<NCHUNK, 256, 0, stream>>>(ei, bucket_cur, rec);
    dinv_kernel<<<NBUCKET, 256, 0, stream>>>(rec, bucket_off, dinv);

    // ---- 4 GCN layers ----
    layer_kernel<F_IN, false><<<NBUCKET, 256, 0, stream>>>(x,  rec, bucket_off, dinv, W0, b0, hA);
    layer_kernel<H_DIM, true><<<NBUCKET, 256, 0, stream>>>(hA, rec, bucket_off, dinv, W1, b1, hB);
    layer_kernel<H_DIM, true><<<NBUCKET, 256, 0, stream>>>(hB, rec, bucket_off, dinv, W2, b2, hA);
    layer_kernel<H_DIM, true><<<NBUCKET, 256, 0, stream>>>(hA, rec, bucket_off, dinv, W3, b3, hB);

    pool_kernel<<<B_GRAPHS, 256, 0, stream>>>(hB, batch, Wout, bout, out);
}

// Round 5
// 342.389 us; speedup vs baseline: 4.1868x; 4.1868x over previous
//
#include <hip/hip_runtime.h>
#include <math.h>

#define N_NODES 100000
#define N_EDGES 1600000
#define F_IN    16
#define H_DIM   32
#define B_GRAPHS 256

#define BSHIFT  7
#define BSIZE   128                                   // nodes per bucket
#define NBUCKET ((N_NODES + BSIZE - 1) / BSIZE)       // 782
#define EPB     8192                                  // edges per chunk block
#define NCHUNK  ((N_EDGES + EPB - 1) / EPB)           // 196
#define CAP     4096                                  // max edges per bucket (mean 2046, std ~45)
#define NPB     16                                    // nodes per layer block
#define LAYER_BLOCKS (N_NODES / NPB)                  // 6250

// ---------------------------------------------------------------------------
__device__ inline float bf_lo(unsigned u) { return __uint_as_float(u << 16); }
__device__ inline float bf_hi(unsigned u) { return __uint_as_float(u & 0xffff0000u); }
__device__ inline unsigned pack_bf16x2(float a, float b) {
    unsigned ua = __float_as_uint(a), ub = __float_as_uint(b);
    ua += 0x7fffu + ((ua >> 16) & 1u);    // RNE
    ub += 0x7fffu + ((ub >> 16) & 1u);
    return (ua >> 16) | (ub & 0xffff0000u);
}

// ---------------------------------------------------------------------------
// Pass A: per-bucket edge histogram (bucket_cnt pre-zeroed)
__global__ __launch_bounds__(256) void passA_kernel(const int* __restrict__ dst,
                                                    int* __restrict__ bucket_cnt) {
    __shared__ int hist[NBUCKET];
    int t = threadIdx.x;
    for (int k = t; k < NBUCKET; k += 256) hist[k] = 0;
    __syncthreads();
    int base = blockIdx.x * EPB;
    int end  = base + EPB; if (end > N_EDGES) end = N_EDGES;
    for (int e = base + t; e < end; e += 256) atomicAdd(&hist[dst[e] >> BSHIFT], 1);
    __syncthreads();
    for (int k = t; k < NBUCKET; k += 256)
        if (hist[k]) atomicAdd(&bucket_cnt[k], hist[k]);
}

// Scan bucket counts -> bucket_off (exclusive, +sentinel) and bucket_cur copy.
__global__ __launch_bounds__(256) void scan_kernel(const int* __restrict__ bucket_cnt,
                                                   int* __restrict__ bucket_off,
                                                   int* __restrict__ bucket_cur) {
    __shared__ int s[1024];
    int t = threadIdx.x;
    int v[4];
    for (int r = 0; r < 4; ++r) {
        int k = t + 256 * r;
        int x = (k < NBUCKET) ? bucket_cnt[k] : 0;
        v[r] = x; s[k] = x;
    }
    __syncthreads();
    for (int off = 1; off < 1024; off <<= 1) {
        int tmp[4];
        for (int r = 0; r < 4; ++r) { int k = t + 256 * r; tmp[r] = (k >= off) ? s[k - off] : 0; }
        __syncthreads();
        for (int r = 0; r < 4; ++r) { int k = t + 256 * r; s[k] += tmp[r]; }
        __syncthreads();
    }
    for (int r = 0; r < 4; ++r) {
        int k = t + 256 * r;
        if (k < NBUCKET) {
            int excl = s[k] - v[r];
            bucket_off[k] = excl;
            bucket_cur[k] = excl;
        }
    }
    if (t == 0) bucket_off[NBUCKET] = s[1023];   // == N_EDGES
}

// Pass B: partition edges into bucket-major order, LDS-staged.
// Record = src (bits 0..19) | dst_local (bits 20..26).
__global__ __launch_bounds__(256) void passB_kernel(const int* __restrict__ ei,
                                                    int* __restrict__ bucket_cur,
                                                    unsigned* __restrict__ rec_out) {
    __shared__ int hist[NBUCKET];
    __shared__ int sbase[NBUCKET];
    __shared__ int gbase[NBUCKET];
    __shared__ int scnt[NBUCKET];
    __shared__ int ssc[1024];
    __shared__ unsigned stage[EPB];
    int t = threadIdx.x;
    for (int k = t; k < NBUCKET; k += 256) { hist[k] = 0; scnt[k] = 0; }
    __syncthreads();

    const int* dst = ei + N_EDGES;
    int base = blockIdx.x * EPB;
    int end  = base + EPB; if (end > N_EDGES) end = N_EDGES;
    int n = end - base;

    for (int e = base + t; e < end; e += 256) atomicAdd(&hist[dst[e] >> BSHIFT], 1);
    __syncthreads();

    int v[4];
    for (int r = 0; r < 4; ++r) {
        int k = t + 256 * r;
        int x = (k < NBUCKET) ? hist[k] : 0;
        v[r] = x; ssc[k] = x;
    }
    __syncthreads();
    for (int off = 1; off < 1024; off <<= 1) {
        int tmp[4];
        for (int r = 0; r < 4; ++r) { int k = t + 256 * r; tmp[r] = (k >= off) ? ssc[k - off] : 0; }
        __syncthreads();
        for (int r = 0; r < 4; ++r) { int k = t + 256 * r; ssc[k] += tmp[r]; }
        __syncthreads();
    }
    for (int r = 0; r < 4; ++r) {
        int k = t + 256 * r;
        if (k < NBUCKET) sbase[k] = ssc[k] - v[r];
    }
    for (int k = t; k < NBUCKET; k += 256) {
        int h = hist[k];
        gbase[k] = h ? atomicAdd(&bucket_cur[k], h) : 0;
    }
    __syncthreads();

    for (int e = base + t; e < end; e += 256) {
        int d = dst[e], s = ei[e];
        int bk = d >> BSHIFT;
        int off = atomicAdd(&scnt[bk], 1);
        stage[sbase[bk] + off] = (unsigned)s | ((unsigned)(d & (BSIZE - 1)) << 20);
    }
    __syncthreads();

    for (int k = t; k < n; k += 256) {
        int lo = 0, hi = NBUCKET - 1;
        while (lo < hi) { int mid = (lo + hi + 1) >> 1; if (sbase[mid] <= k) lo = mid; else hi = mid - 1; }
        rec_out[gbase[lo] + (k - sbase[lo])] = stage[k];
    }
}

// Per-bucket in-degree -> dinv (needs rec, bucket-major; runs before passC)
__global__ __launch_bounds__(256) void dinv_kernel(const unsigned* __restrict__ rec,
                                                   const int* __restrict__ bucket_off,
                                                   float* __restrict__ dinv) {
    __shared__ int cnt[BSIZE];
    int t = threadIdx.x, b = blockIdx.x;
    if (t < BSIZE) cnt[t] = 0;
    __syncthreads();
    int e1 = bucket_off[b + 1];
    for (int e = bucket_off[b] + t; e < e1; e += 256) atomicAdd(&cnt[rec[e] >> 20], 1);
    __syncthreads();
    int nd = (b << BSHIFT) + t;
    if (t < BSIZE && nd < N_NODES) dinv[nd] = rsqrtf((float)cnt[t] + 1.0f);
}

// Pass C: sort each bucket's edges to node-major CSR; write csr_src + csr_coef
// (block-owned contiguous segment -> no cross-XCD write ping-pong) + row_start.
__global__ __launch_bounds__(256) void passC_kernel(const unsigned* __restrict__ rec,
                                                    const int* __restrict__ bucket_off,
                                                    const float* __restrict__ dinv,
                                                    int* __restrict__ row_start,
                                                    int* __restrict__ csr_src,
                                                    float* __restrict__ csr_coef) {
    __shared__ unsigned stage[CAP];
    __shared__ int cnt[BSIZE];
    __shared__ int sc[BSIZE];
    __shared__ int cur[BSIZE];
    __shared__ float sdv[BSIZE];
    int t = threadIdx.x, b = blockIdx.x;
    int node0 = b << BSHIFT;
    int e0 = bucket_off[b], e1 = bucket_off[b + 1];
    int n = e1 - e0;                      // <= CAP (22-sigma margin)
    if (t < BSIZE) {
        cnt[t] = 0;
        int nd = node0 + t;
        sdv[t] = (nd < N_NODES) ? dinv[nd] : 0.f;
    }
    __syncthreads();
    for (int k = t; k < n; k += 256) {
        unsigned r = rec[e0 + k];
        stage[k] = r;
        atomicAdd(&cnt[r >> 20], 1);
    }
    __syncthreads();
    // exclusive scan of cnt[128]
    if (t < BSIZE) sc[t] = cnt[t];
    __syncthreads();
    for (int off = 1; off < BSIZE; off <<= 1) {
        int v = (t < BSIZE && t >= off) ? sc[t - off] : 0;
        __syncthreads();
        if (t < BSIZE) sc[t] += v;
        __syncthreads();
    }
    if (t < BSIZE) {
        int ex = sc[t] - cnt[t];
        cur[t] = ex;
        row_start[node0 + t] = e0 + ex;
    }
    __syncthreads();
    // scatter into block-owned global segment (L2-local, full lines written once)
    for (int k = t; k < n; k += 256) {
        unsigned r = stage[k];
        int dl = r >> 20;
        int s  = r & 0xFFFFF;
        int pos = atomicAdd(&cur[dl], 1);
        csr_src[e0 + pos]  = s;
        csr_coef[e0 + pos] = dinv[s] * sdv[dl];
    }
}

// ---------------------------------------------------------------------------
// GCN layer: gather aggregation (no atomics), 16 lanes/node, edge loop
// hand-unrolled x4 for memory-level parallelism; fused W + bias + tanh + pack.
template <int FIN, bool PACKED>
__global__ __launch_bounds__(256) void layer_kernel(
        const void* __restrict__ h_in_v,
        const int* __restrict__ row_start,
        const int* __restrict__ csr_src,
        const float* __restrict__ csr_coef,
        const float* __restrict__ dinv,
        const float* __restrict__ W,       // [FIN][32]
        const float* __restrict__ bias,    // [32]
        unsigned* __restrict__ h_out) {
    constexpr int STR = FIN + 1;
    __shared__ float sW[FIN * H_DIM];
    __shared__ float sb[H_DIM];
    __shared__ float agg[NPB][STR];
    int t = threadIdx.x;
    for (int k = t; k < FIN * H_DIM; k += 256) sW[k] = W[k];
    if (t < H_DIM) sb[t] = bias[t];

    int nl = t >> 4, ln = t & 15;
    int i = blockIdx.x * NPB + nl;
    int start = row_start[i];
    int end   = row_start[i + 1];
    float di  = dinv[i];
    float di2 = di * di;

    if (PACKED) {
        const unsigned* hp = (const unsigned*)h_in_v;
        unsigned u = hp[i * 16 + ln];
        float acc0 = bf_lo(u) * di2, acc1 = bf_hi(u) * di2;
        int e = start;
        for (; e + 4 <= end; e += 4) {
            int s0 = csr_src[e], s1 = csr_src[e + 1], s2 = csr_src[e + 2], s3 = csr_src[e + 3];
            float c0 = csr_coef[e], c1 = csr_coef[e + 1], c2 = csr_coef[e + 2], c3 = csr_coef[e + 3];
            unsigned v0 = hp[s0 * 16 + ln], v1 = hp[s1 * 16 + ln];
            unsigned v2 = hp[s2 * 16 + ln], v3 = hp[s3 * 16 + ln];
            acc0 += bf_lo(v0) * c0 + bf_lo(v1) * c1 + bf_lo(v2) * c2 + bf_lo(v3) * c3;
            acc1 += bf_hi(v0) * c0 + bf_hi(v1) * c1 + bf_hi(v2) * c2 + bf_hi(v3) * c3;
        }
        for (; e < end; ++e) {
            unsigned v = hp[csr_src[e] * 16 + ln];
            float c = csr_coef[e];
            acc0 += bf_lo(v) * c;
            acc1 += bf_hi(v) * c;
        }
        agg[nl][2 * ln]     = acc0;
        agg[nl][2 * ln + 1] = acc1;
    } else {
        const float* xf = (const float*)h_in_v;
        float acc = xf[i * F_IN + ln] * di2;
        int e = start;
        for (; e + 4 <= end; e += 4) {
            int s0 = csr_src[e], s1 = csr_src[e + 1], s2 = csr_src[e + 2], s3 = csr_src[e + 3];
            float c0 = csr_coef[e], c1 = csr_coef[e + 1], c2 = csr_coef[e + 2], c3 = csr_coef[e + 3];
            acc += xf[s0 * F_IN + ln] * c0 + xf[s1 * F_IN + ln] * c1
                 + xf[s2 * F_IN + ln] * c2 + xf[s3 * F_IN + ln] * c3;
        }
        for (; e < end; ++e) acc += xf[csr_src[e] * F_IN + ln] * csr_coef[e];
        agg[nl][ln] = acc;
    }
    __syncthreads();

    // transform + bias + tanh + pack  (256 threads = 16 nodes x 16 feat-pairs)
    {
        int j0 = 2 * ln;
        float o0 = sb[j0], o1 = sb[j0 + 1];
        const float* arow = &agg[nl][0];
#pragma unroll
        for (int k = 0; k < FIN; ++k) {
            float a = arow[k];
            o0 += a * sW[k * H_DIM + j0];
            o1 += a * sW[k * H_DIM + j0 + 1];
        }
        h_out[i * 16 + ln] = pack_bf16x2(tanhf(o0), tanhf(o1));
    }
}

// ---------------------------------------------------------------------------
// Per-graph pooling (batch sorted) + linear head, reading packed bf16 h.
__global__ __launch_bounds__(256) void pool_kernel(const unsigned* __restrict__ hp,
                                                   const int* __restrict__ batch,
                                                   const float* __restrict__ Wout,
                                                   const float* __restrict__ bout,
                                                   float* __restrict__ out) {
    int b = blockIdx.x;
    int t = threadIdx.x;
    int lane_n = t >> 5;
    int j = t & 31;

    int lo = 0, hi = N_NODES;
    while (lo < hi) { int mid = (lo + hi) >> 1; if (batch[mid] < b) lo = mid + 1; else hi = mid; }
    int start = lo;
    hi = N_NODES;
    while (lo < hi) { int mid = (lo + hi) >> 1; if (batch[mid] < b + 1) lo = mid + 1; else hi = mid; }
    int end = lo;

    float vmax = -INFINITY, vsum = 0.f;
    for (int i = start + lane_n; i < end; i += 8) {
        unsigned q = hp[i * 16 + (j >> 1)];
        float v = (j & 1) ? bf_hi(q) : bf_lo(q);
        vmax = fmaxf(vmax, v);
        vsum += v;
    }

    __shared__ float smax[8][32];
    __shared__ float ssum[8][32];
    __shared__ float pool96[96];
    smax[lane_n][j] = vmax;
    ssum[lane_n][j] = vsum;
    __syncthreads();

    if (t < 32) {
        float m = smax[0][t], s = ssum[0][t];
#pragma unroll
        for (int n = 1; n < 8; ++n) { m = fmaxf(m, smax[n][t]); s += ssum[n][t]; }
        int cnt = end - start;
        float mean = s / fmaxf((float)cnt, 1.0f);
        pool96[t]      = m;
        pool96[32 + t] = mean;
        pool96[64 + t] = s;
    }
    __syncthreads();

    if (t < 96) out[B_GRAPHS + b * 96 + t] = pool96[t];

    __shared__ float dotbuf[96];
    if (t < 96) dotbuf[t] = pool96[t] * Wout[t];
    __syncthreads();
    if (t == 0) {
        float acc = 0.f;
#pragma unroll
        for (int k = 0; k < 96; ++k) acc += dotbuf[k];
        out[b] = acc + bout[0];
    }
}

// ---------------------------------------------------------------------------
extern "C" void kernel_launch(void* const* d_in, const int* in_sizes, int n_in,
                              void* d_out, int out_size, void* d_ws, size_t ws_size,
                              hipStream_t stream) {
    const float* x     = (const float*)d_in[0];
    const int*   ei    = (const int*)  d_in[1];   // src = ei[0:E], dst = ei[E:2E]
    const int*   batch = (const int*)  d_in[2];
    const float* W0    = (const float*)d_in[3];
    const float* b0    = (const float*)d_in[4];
    const float* W1    = (const float*)d_in[5];
    const float* b1    = (const float*)d_in[6];
    const float* W2    = (const float*)d_in[7];
    const float* b2    = (const float*)d_in[8];
    const float* W3    = (const float*)d_in[9];
    const float* b3    = (const float*)d_in[10];
    const float* Wout  = (const float*)d_in[11];
    const float* bout  = (const float*)d_in[12];
    float* out = (float*)d_out;

    char* p = (char*)d_ws;
    float*    dinv       = (float*)p;    p += (size_t)N_NODES * 4;
    unsigned* hA         = (unsigned*)p; p += (size_t)N_NODES * 16 * 4;
    unsigned* hB         = (unsigned*)p; p += (size_t)N_NODES * 16 * 4;
    unsigned* rec        = (unsigned*)p; p += (size_t)N_EDGES * 4;
    int*      csr_src    = (int*)p;      p += (size_t)N_EDGES * 4;
    float*    csr_coef   = (float*)p;    p += (size_t)N_EDGES * 4;
    int*      row_start  = (int*)p;      p += (size_t)(N_NODES + BSIZE + 1) * 4;
    int*      bucket_cnt = (int*)p;      p += NBUCKET * 4;
    int*      bucket_off = (int*)p;      p += (NBUCKET + 1) * 4;
    int*      bucket_cur = (int*)p;      p += NBUCKET * 4;

    // ---- edge build: bucket partition -> per-bucket node sort -> CSR ----
    hipMemsetAsync(bucket_cnt, 0, NBUCKET * sizeof(int), stream);
    passA_kernel<<<NCHUNK, 256, 0, stream>>>(ei + N_EDGES, bucket_cnt);
    scan_kernel<<<1, 256, 0, stream>>>(bucket_cnt, bucket_off, bucket_cur);
    passB_kernel<<<NCHUNK, 256, 0, stream>>>(ei, bucket_cur, rec);
    dinv_kernel<<<NBUCKET, 256, 0, stream>>>(rec, bucket_off, dinv);
    passC_kernel<<<NBUCKET, 256, 0, stream>>>(rec, bucket_off, dinv,
                                              row_start, csr_src, csr_coef);

    // ---- 4 GCN layers (gather, no atomics) ----
    layer_kernel<F_IN, false><<<LAYER_BLOCKS, 256, 0, stream>>>(
        x,  row_start, csr_src, csr_coef, dinv, W0, b0, hA);
    layer_kernel<H_DIM, true><<<LAYER_BLOCKS, 256, 0, stream>>>(
        hA, row_start, csr_src, csr_coef, dinv, W1, b1, hB);
    layer_kernel<H_DIM, true><<<LAYER_BLOCKS, 256, 0, stream>>>(
        hB, row_start, csr_src, csr_coef, dinv, W2, b2, hA);
    layer_kernel<H_DIM, true><<<LAYER_BLOCKS, 256, 0, stream>>>(
        hA, row_start, csr_src, csr_coef, dinv, W3, b3, hB);

    pool_kernel<<<B_GRAPHS, 256, 0, stream>>>(hB, batch, Wout, bout, out);
}

// Round 6
// 316.141 us; speedup vs baseline: 4.5344x; 1.0830x over previous
//
#include <hip/hip_runtime.h>
#include <math.h>

#define N_NODES 100000
#define N_EDGES 1600000
#define F_IN    16
#define H_DIM   32
#define B_GRAPHS 256

#define BSHIFT  7
#define BSIZE   128                                   // nodes per bucket
#define NBUCKET ((N_NODES + BSIZE - 1) / BSIZE)       // 782
#define EPB     8192                                  // edges per chunk block
#define NCHUNK  ((N_EDGES + EPB - 1) / EPB)           // 196
#define CAP     4096                                  // max edges per bucket (mean 2046, std ~45)
#define PADR    (BSIZE * 7)                           // per-bucket pad reservation (896)
#define TPAD    (N_EDGES + NBUCKET * PADR)            // padded CSR entries (2,300,672)
#define NPB     16                                    // nodes per layer block
#define LAYER_BLOCKS (N_NODES / NPB)                  // 6250

// ---------------------------------------------------------------------------
__device__ inline float bf_lo(unsigned u) { return __uint_as_float(u << 16); }
__device__ inline float bf_hi(unsigned u) { return __uint_as_float(u & 0xffff0000u); }
__device__ inline unsigned pack_bf16x2(float a, float b) {
    unsigned ua = __float_as_uint(a), ub = __float_as_uint(b);
    ua += 0x7fffu + ((ua >> 16) & 1u);    // RNE
    ub += 0x7fffu + ((ub >> 16) & 1u);
    return (ua >> 16) | (ub & 0xffff0000u);
}

// ---------------------------------------------------------------------------
// Pass A: per-bucket edge histogram (bucket_cnt pre-zeroed)
__global__ __launch_bounds__(256) void passA_kernel(const int* __restrict__ dst,
                                                    int* __restrict__ bucket_cnt) {
    __shared__ int hist[NBUCKET];
    int t = threadIdx.x;
    for (int k = t; k < NBUCKET; k += 256) hist[k] = 0;
    __syncthreads();
    int base = blockIdx.x * EPB;
    int end  = base + EPB; if (end > N_EDGES) end = N_EDGES;
    for (int e = base + t; e < end; e += 256) atomicAdd(&hist[dst[e] >> BSHIFT], 1);
    __syncthreads();
    for (int k = t; k < NBUCKET; k += 256)
        if (hist[k]) atomicAdd(&bucket_cnt[k], hist[k]);
}

// Scan bucket counts -> bucket_off (exclusive, +sentinel) and bucket_cur copy.
__global__ __launch_bounds__(256) void scan_kernel(const int* __restrict__ bucket_cnt,
                                                   int* __restrict__ bucket_off,
                                                   int* __restrict__ bucket_cur) {
    __shared__ int s[1024];
    int t = threadIdx.x;
    int v[4];
    for (int r = 0; r < 4; ++r) {
        int k = t + 256 * r;
        int x = (k < NBUCKET) ? bucket_cnt[k] : 0;
        v[r] = x; s[k] = x;
    }
    __syncthreads();
    for (int off = 1; off < 1024; off <<= 1) {
        int tmp[4];
        for (int r = 0; r < 4; ++r) { int k = t + 256 * r; tmp[r] = (k >= off) ? s[k - off] : 0; }
        __syncthreads();
        for (int r = 0; r < 4; ++r) { int k = t + 256 * r; s[k] += tmp[r]; }
        __syncthreads();
    }
    for (int r = 0; r < 4; ++r) {
        int k = t + 256 * r;
        if (k < NBUCKET) {
            int excl = s[k] - v[r];
            bucket_off[k] = excl;
            bucket_cur[k] = excl;
        }
    }
    if (t == 0) bucket_off[NBUCKET] = s[1023];   // == N_EDGES
}

// Pass B: partition edges into bucket-major order, LDS-staged.
// Record = src (bits 0..19) | dst_local (bits 20..26).
// Stream-out: wave-per-bucket run copy (no binary search).
__global__ __launch_bounds__(256) void passB_kernel(const int* __restrict__ ei,
                                                    int* __restrict__ bucket_cur,
                                                    unsigned* __restrict__ rec_out) {
    __shared__ int hist[NBUCKET];
    __shared__ int sbase[NBUCKET];
    __shared__ int gbase[NBUCKET];
    __shared__ int scnt[NBUCKET];
    __shared__ int ssc[1024];
    __shared__ unsigned stage[EPB];
    int t = threadIdx.x;
    for (int k = t; k < NBUCKET; k += 256) { hist[k] = 0; scnt[k] = 0; }
    __syncthreads();

    const int* dst = ei + N_EDGES;
    int base = blockIdx.x * EPB;
    int end  = base + EPB; if (end > N_EDGES) end = N_EDGES;

    for (int e = base + t; e < end; e += 256) atomicAdd(&hist[dst[e] >> BSHIFT], 1);
    __syncthreads();

    int v[4];
    for (int r = 0; r < 4; ++r) {
        int k = t + 256 * r;
        int x = (k < NBUCKET) ? hist[k] : 0;
        v[r] = x; ssc[k] = x;
    }
    __syncthreads();
    for (int off = 1; off < 1024; off <<= 1) {
        int tmp[4];
        for (int r = 0; r < 4; ++r) { int k = t + 256 * r; tmp[r] = (k >= off) ? ssc[k - off] : 0; }
        __syncthreads();
        for (int r = 0; r < 4; ++r) { int k = t + 256 * r; ssc[k] += tmp[r]; }
        __syncthreads();
    }
    for (int r = 0; r < 4; ++r) {
        int k = t + 256 * r;
        if (k < NBUCKET) sbase[k] = ssc[k] - v[r];
    }
    for (int k = t; k < NBUCKET; k += 256) {
        int h = hist[k];
        gbase[k] = h ? atomicAdd(&bucket_cur[k], h) : 0;
    }
    __syncthreads();

    for (int e = base + t; e < end; e += 256) {
        int d = dst[e], s = ei[e];
        int bk = d >> BSHIFT;
        int off = atomicAdd(&scnt[bk], 1);
        stage[sbase[bk] + off] = (unsigned)s | ((unsigned)(d & (BSIZE - 1)) << 20);
    }
    __syncthreads();

    // wave w copies buckets w, w+4, ... (contiguous runs, coalesced-ish)
    int wave = t >> 6, lane = t & 63;
    for (int bk = wave; bk < NBUCKET; bk += 4) {
        int h = hist[bk];
        if (h == 0) continue;
        int sb = sbase[bk], gb = gbase[bk];
        for (int j = lane; j < h; j += 64)
            rec_out[gb + j] = stage[sb + j];
    }
}

// Per-bucket in-degree -> dinv
__global__ __launch_bounds__(256) void dinv_kernel(const unsigned* __restrict__ rec,
                                                   const int* __restrict__ bucket_off,
                                                   float* __restrict__ dinv) {
    __shared__ int cnt[BSIZE];
    int t = threadIdx.x, b = blockIdx.x;
    if (t < BSIZE) cnt[t] = 0;
    __syncthreads();
    int e1 = bucket_off[b + 1];
    for (int e = bucket_off[b] + t; e < e1; e += 256) atomicAdd(&cnt[rec[e] >> 20], 1);
    __syncthreads();
    int nd = (b << BSHIFT) + t;
    if (t < BSIZE && nd < N_NODES) dinv[nd] = rsqrtf((float)cnt[t] + 1.0f);
}

// Pass C: sort each bucket's edges to node-major CSR with rows PADDED to
// multiples of 8 (dummy src=0 coef=0). Writes csr_src/csr_coef (block-owned
// contiguous region) + row_meta = (start, padded_len).
__global__ __launch_bounds__(256) void passC_kernel(const unsigned* __restrict__ rec,
                                                    const int* __restrict__ bucket_off,
                                                    const float* __restrict__ dinv,
                                                    int2* __restrict__ row_meta,
                                                    int* __restrict__ csr_src,
                                                    float* __restrict__ csr_coef) {
    __shared__ unsigned stage[CAP];
    __shared__ int cnt[BSIZE];
    __shared__ int pds[BSIZE];
    __shared__ int cur[BSIZE];
    __shared__ float sdv[BSIZE];
    int t = threadIdx.x, b = blockIdx.x;
    int node0 = b << BSHIFT;
    int e0 = bucket_off[b], e1 = bucket_off[b + 1];
    int n = e1 - e0;
    int pbase = e0 + b * PADR;
    if (t < BSIZE) {
        cnt[t] = 0;
        int nd = node0 + t;
        sdv[t] = (nd < N_NODES) ? dinv[nd] : 0.f;
    }
    __syncthreads();
    for (int k = t; k < n; k += 256) {
        unsigned r = rec[e0 + k];
        stage[k] = r;
        atomicAdd(&cnt[r >> 20], 1);
    }
    __syncthreads();
    // inclusive scan of padded counts
    int pd = 0;
    if (t < BSIZE) { pd = (cnt[t] + 7) & ~7; pds[t] = pd; }
    __syncthreads();
    for (int off = 1; off < BSIZE; off <<= 1) {
        int v = (t < BSIZE && t >= off) ? pds[t - off] : 0;
        __syncthreads();
        if (t < BSIZE) pds[t] += v;
        __syncthreads();
    }
    if (t < BSIZE) {
        int startp = pbase + pds[t] - pd;
        cur[t] = startp;
        int nd = node0 + t;
        if (nd < N_NODES) row_meta[nd] = make_int2(startp, pd);
        // dummy-fill this node's pad slots
        for (int k = startp + cnt[t]; k < startp + pd; ++k) {
            csr_src[k]  = 0;
            csr_coef[k] = 0.f;
        }
    }
    __syncthreads();
    for (int k = t; k < n; k += 256) {
        unsigned r = stage[k];
        int dl = r >> 20;
        int s  = r & 0xFFFFF;
        int pos = atomicAdd(&cur[dl], 1);
        csr_src[pos]  = s;
        csr_coef[pos] = dinv[s] * sdv[dl];
    }
}

// ---------------------------------------------------------------------------
// GCN layer: gather aggregation, branch-free chunks of 8 (rows padded),
// 8 independent gathers in flight; fused W + bias + tanh + bf16x2 pack.
template <int FIN, bool PACKED>
__global__ __launch_bounds__(256) void layer_kernel(
        const void* __restrict__ h_in_v,
        const int2* __restrict__ row_meta,
        const int* __restrict__ csr_src,
        const float* __restrict__ csr_coef,
        const float* __restrict__ dinv,
        const float* __restrict__ W,       // [FIN][32]
        const float* __restrict__ bias,    // [32]
        unsigned* __restrict__ h_out) {
    constexpr int STR = FIN + 1;
    __shared__ float sW[FIN * H_DIM];
    __shared__ float sb[H_DIM];
    __shared__ float agg[NPB][STR];
    int t = threadIdx.x;
    for (int k = t; k < FIN * H_DIM; k += 256) sW[k] = W[k];
    if (t < H_DIM) sb[t] = bias[t];

    int nl = t >> 4, ln = t & 15;
    int i = blockIdx.x * NPB + nl;
    int2 m = row_meta[i];
    float di = dinv[i], di2 = di * di;
    int eend = m.x + m.y;

    if (PACKED) {
        const unsigned* hp = (const unsigned*)h_in_v;
        unsigned u = hp[i * 16 + ln];
        float acc0 = bf_lo(u) * di2, acc1 = bf_hi(u) * di2;
        for (int e = m.x; e < eend; e += 8) {
            int s[8]; float c[8]; unsigned v[8];
#pragma unroll
            for (int k = 0; k < 8; ++k) { s[k] = csr_src[e + k]; c[k] = csr_coef[e + k]; }
#pragma unroll
            for (int k = 0; k < 8; ++k) v[k] = hp[s[k] * 16 + ln];
#pragma unroll
            for (int k = 0; k < 8; ++k) { acc0 += bf_lo(v[k]) * c[k]; acc1 += bf_hi(v[k]) * c[k]; }
        }
        agg[nl][2 * ln]     = acc0;
        agg[nl][2 * ln + 1] = acc1;
    } else {
        const float* xf = (const float*)h_in_v;
        float acc = xf[i * F_IN + ln] * di2;
        for (int e = m.x; e < eend; e += 8) {
            int s[8]; float c[8]; float v[8];
#pragma unroll
            for (int k = 0; k < 8; ++k) { s[k] = csr_src[e + k]; c[k] = csr_coef[e + k]; }
#pragma unroll
            for (int k = 0; k < 8; ++k) v[k] = xf[s[k] * F_IN + ln];
#pragma unroll
            for (int k = 0; k < 8; ++k) acc += v[k] * c[k];
        }
        agg[nl][ln] = acc;
    }
    __syncthreads();

    // transform + bias + tanh + pack  (16 nodes x 16 feat-pairs)
    int j0 = 2 * ln;
    float o0 = sb[j0], o1 = sb[j0 + 1];
    const float* arow = &agg[nl][0];
#pragma unroll
    for (int k = 0; k < FIN; ++k) {
        float a = arow[k];
        o0 += a * sW[k * H_DIM + j0];
        o1 += a * sW[k * H_DIM + j0 + 1];
    }
    h_out[i * 16 + ln] = pack_bf16x2(tanhf(o0), tanhf(o1));
}

// ---------------------------------------------------------------------------
// Per-graph pooling (batch sorted) + linear head, reading packed bf16 h.
__global__ __launch_bounds__(256) void pool_kernel(const unsigned* __restrict__ hp,
                                                   const int* __restrict__ batch,
                                                   const float* __restrict__ Wout,
                                                   const float* __restrict__ bout,
                                                   float* __restrict__ out) {
    int b = blockIdx.x;
    int t = threadIdx.x;
    int lane_n = t >> 5;
    int j = t & 31;

    int lo = 0, hi = N_NODES;
    while (lo < hi) { int mid = (lo + hi) >> 1; if (batch[mid] < b) lo = mid + 1; else hi = mid; }
    int start = lo;
    hi = N_NODES;
    while (lo < hi) { int mid = (lo + hi) >> 1; if (batch[mid] < b + 1) lo = mid + 1; else hi = mid; }
    int end = lo;

    float vmax = -INFINITY, vsum = 0.f;
    for (int i = start + lane_n; i < end; i += 8) {
        unsigned q = hp[i * 16 + (j >> 1)];
        float v = (j & 1) ? bf_hi(q) : bf_lo(q);
        vmax = fmaxf(vmax, v);
        vsum += v;
    }

    __shared__ float smax[8][32];
    __shared__ float ssum[8][32];
    __shared__ float pool96[96];
    smax[lane_n][j] = vmax;
    ssum[lane_n][j] = vsum;
    __syncthreads();

    if (t < 32) {
        float m = smax[0][t], s = ssum[0][t];
#pragma unroll
        for (int n = 1; n < 8; ++n) { m = fmaxf(m, smax[n][t]); s += ssum[n][t]; }
        int cnt = end - start;
        float mean = s / fmaxf((float)cnt, 1.0f);
        pool96[t]      = m;
        pool96[32 + t] = mean;
        pool96[64 + t] = s;
    }
    __syncthreads();

    if (t < 96) out[B_GRAPHS + b * 96 + t] = pool96[t];

    __shared__ float dotbuf[96];
    if (t < 96) dotbuf[t] = pool96[t] * Wout[t];
    __syncthreads();
    if (t == 0) {
        float acc = 0.f;
#pragma unroll
        for (int k = 0; k < 96; ++k) acc += dotbuf[k];
        out[b] = acc + bout[0];
    }
}

// ---------------------------------------------------------------------------
extern "C" void kernel_launch(void* const* d_in, const int* in_sizes, int n_in,
                              void* d_out, int out_size, void* d_ws, size_t ws_size,
                              hipStream_t stream) {
    const float* x     = (const float*)d_in[0];
    const int*   ei    = (const int*)  d_in[1];   // src = ei[0:E], dst = ei[E:2E]
    const int*   batch = (const int*)  d_in[2];
    const float* W0    = (const float*)d_in[3];
    const float* b0    = (const float*)d_in[4];
    const float* W1    = (const float*)d_in[5];
    const float* b1    = (const float*)d_in[6];
    const float* W2    = (const float*)d_in[7];
    const float* b2    = (const float*)d_in[8];
    const float* W3    = (const float*)d_in[9];
    const float* b3    = (const float*)d_in[10];
    const float* Wout  = (const float*)d_in[11];
    const float* bout  = (const float*)d_in[12];
    float* out = (float*)d_out;

    char* p = (char*)d_ws;
    float*    dinv       = (float*)p;    p += (size_t)N_NODES * 4;
    unsigned* hA         = (unsigned*)p; p += (size_t)N_NODES * 16 * 4;
    unsigned* rec        = (unsigned*)p; p += (size_t)N_EDGES * 4;   // reused as hB after passC
    int*      csr_src    = (int*)p;      p += (size_t)TPAD * 4;
    float*    csr_coef   = (float*)p;    p += (size_t)TPAD * 4;
    int2*     row_meta   = (int2*)p;     p += (size_t)N_NODES * 8;
    int*      bucket_cnt = (int*)p;      p += NBUCKET * 4;
    int*      bucket_off = (int*)p;      p += (NBUCKET + 1) * 4;
    int*      bucket_cur = (int*)p;      p += NBUCKET * 4;
    unsigned* hB = rec;   // alias: rec dead once passC completes

    // ---- edge build: bucket partition -> per-bucket node sort -> padded CSR ----
    hipMemsetAsync(bucket_cnt, 0, NBUCKET * sizeof(int), stream);
    passA_kernel<<<NCHUNK, 256, 0, stream>>>(ei + N_EDGES, bucket_cnt);
    scan_kernel<<<1, 256, 0, stream>>>(bucket_cnt, bucket_off, bucket_cur);
    passB_kernel<<<NCHUNK, 256, 0, stream>>>(ei, bucket_cur, rec);
    dinv_kernel<<<NBUCKET, 256, 0, stream>>>(rec, bucket_off, dinv);
    passC_kernel<<<NBUCKET, 256, 0, stream>>>(rec, bucket_off, dinv,
                                              row_meta, csr_src, csr_coef);

    // ---- 4 GCN layers (gather, no atomics, 8-deep MLP) ----
    layer_kernel<F_IN, false><<<LAYER_BLOCKS, 256, 0, stream>>>(
        x,  row_meta, csr_src, csr_coef, dinv, W0, b0, hA);
    layer_kernel<H_DIM, true><<<LAYER_BLOCKS, 256, 0, stream>>>(
        hA, row_meta, csr_src, csr_coef, dinv, W1, b1, hB);
    layer_kernel<H_DIM, true><<<LAYER_BLOCKS, 256, 0, stream>>>(
        hB, row_meta, csr_src, csr_coef, dinv, W2, b2, hA);
    layer_kernel<H_DIM, true><<<LAYER_BLOCKS, 256, 0, stream>>>(
        hA, row_meta, csr_src, csr_coef, dinv, W3, b3, hB);

    pool_kernel<<<B_GRAPHS, 256, 0, stream>>>(hB, batch, Wout, bout, out);
}

// Round 7
// 277.929 us; speedup vs baseline: 5.1579x; 1.1375x over previous
//
#include <hip/hip_runtime.h>
#include <math.h>

#define N_NODES 100000
#define N_EDGES 1600000
#define F_IN    16
#define H_DIM   32
#define B_GRAPHS 256

#define BSHIFT  7
#define BSIZE   128                                   // nodes per bucket
#define NBUCKET ((N_NODES + BSIZE - 1) / BSIZE)       // 782
#define EPB     8192                                  // edges per chunk block
#define NCHUNK  ((N_EDGES + EPB - 1) / EPB)           // 196
#define CAP     4096                                  // max edges per bucket (mean 2046, ~45 sigma)
#define PADR2   904                                   // per-bucket pad+align reservation
#define TPAD    (N_EDGES + NBUCKET * PADR2)           // padded CSR entries
#define NPB     16                                    // nodes per layer block
#define LAYER_BLOCKS (N_NODES / NPB)                  // 6250

// ---------------------------------------------------------------------------
__device__ inline float bf_lo(unsigned u) { return __uint_as_float(u << 16); }
__device__ inline float bf_hi(unsigned u) { return __uint_as_float(u & 0xffff0000u); }
__device__ inline unsigned pack_bf16x2(float a, float b) {
    unsigned ua = __float_as_uint(a), ub = __float_as_uint(b);
    ua += 0x7fffu + ((ua >> 16) & 1u);    // RNE
    ub += 0x7fffu + ((ub >> 16) & 1u);
    return (ua >> 16) | (ub & 0xffff0000u);
}

// ---------------------------------------------------------------------------
// Pass A: per-bucket edge histogram (bucket_cnt pre-zeroed)
__global__ __launch_bounds__(256) void passA_kernel(const int* __restrict__ dst,
                                                    int* __restrict__ bucket_cnt) {
    __shared__ int hist[NBUCKET];
    int t = threadIdx.x;
    for (int k = t; k < NBUCKET; k += 256) hist[k] = 0;
    __syncthreads();
    int base = blockIdx.x * EPB;
    int end  = base + EPB; if (end > N_EDGES) end = N_EDGES;
    for (int e = base + t; e < end; e += 256) atomicAdd(&hist[dst[e] >> BSHIFT], 1);
    __syncthreads();
    for (int k = t; k < NBUCKET; k += 256)
        if (hist[k]) atomicAdd(&bucket_cnt[k], hist[k]);
}

// Scan bucket counts -> bucket_off (exclusive, +sentinel) and bucket_cur copy.
__global__ __launch_bounds__(256) void scan_kernel(const int* __restrict__ bucket_cnt,
                                                   int* __restrict__ bucket_off,
                                                   int* __restrict__ bucket_cur) {
    __shared__ int s[1024];
    int t = threadIdx.x;
    int v[4];
    for (int r = 0; r < 4; ++r) {
        int k = t + 256 * r;
        int x = (k < NBUCKET) ? bucket_cnt[k] : 0;
        v[r] = x; s[k] = x;
    }
    __syncthreads();
    for (int off = 1; off < 1024; off <<= 1) {
        int tmp[4];
        for (int r = 0; r < 4; ++r) { int k = t + 256 * r; tmp[r] = (k >= off) ? s[k - off] : 0; }
        __syncthreads();
        for (int r = 0; r < 4; ++r) { int k = t + 256 * r; s[k] += tmp[r]; }
        __syncthreads();
    }
    for (int r = 0; r < 4; ++r) {
        int k = t + 256 * r;
        if (k < NBUCKET) {
            int excl = s[k] - v[r];
            bucket_off[k] = excl;
            bucket_cur[k] = excl;
        }
    }
    if (t == 0) bucket_off[NBUCKET] = s[1023];   // == N_EDGES
}

// Pass B: per-block histogram -> claim per-bucket global ranges -> DIRECT
// scattered writes (consecutive within (block,bucket) run; no LDS staging,
// no serial copy-out). Record = src | dst_local<<20.
__global__ __launch_bounds__(256) void passB_kernel(const int* __restrict__ ei,
                                                    int* __restrict__ bucket_cur,
                                                    unsigned* __restrict__ rec_out) {
    __shared__ int hist[NBUCKET];
    __shared__ int gcur[NBUCKET];
    int t = threadIdx.x;
    for (int k = t; k < NBUCKET; k += 256) hist[k] = 0;
    __syncthreads();

    const int* dst = ei + N_EDGES;
    int base = blockIdx.x * EPB;
    int end  = base + EPB; if (end > N_EDGES) end = N_EDGES;

    for (int e = base + t; e < end; e += 256) atomicAdd(&hist[dst[e] >> BSHIFT], 1);
    __syncthreads();

    for (int k = t; k < NBUCKET; k += 256) {
        int h = hist[k];
        gcur[k] = h ? atomicAdd(&bucket_cur[k], h) : 0;
    }
    __syncthreads();

    for (int e = base + t; e < end; e += 256) {
        int d = dst[e], s = ei[e];
        int bk = d >> BSHIFT;
        int pos = atomicAdd(&gcur[bk], 1);
        rec_out[pos] = (unsigned)s | ((unsigned)(d & (BSIZE - 1)) << 20);
    }
}

// Per-bucket in-degree -> dinv
__global__ __launch_bounds__(256) void dinv_kernel(const unsigned* __restrict__ rec,
                                                   const int* __restrict__ bucket_off,
                                                   float* __restrict__ dinv) {
    __shared__ int cnt[BSIZE];
    int t = threadIdx.x, b = blockIdx.x;
    if (t < BSIZE) cnt[t] = 0;
    __syncthreads();
    int e1 = bucket_off[b + 1];
    for (int e = bucket_off[b] + t; e < e1; e += 256) atomicAdd(&cnt[rec[e] >> 20], 1);
    __syncthreads();
    int nd = (b << BSHIFT) + t;
    if (t < BSIZE && nd < N_NODES) dinv[nd] = rsqrtf((float)cnt[t] + 1.0f);
}

// Pass C: per-bucket node sort into padded, INTERLEAVED CSR: entry = (src,
// coef-as-int). Rows padded to multiples of 8 entries; row starts 8-aligned
// (=> 16B-aligned int4 loads in the layers). row_meta = (start, padded_len).
__global__ __launch_bounds__(256) void passC_kernel(const unsigned* __restrict__ rec,
                                                    const int* __restrict__ bucket_off,
                                                    const float* __restrict__ dinv,
                                                    int2* __restrict__ row_meta,
                                                    int2* __restrict__ csr,
                                                    const int* __restrict__ dummy_unused) {
    __shared__ unsigned stage[CAP];
    __shared__ int cnt[BSIZE];
    __shared__ int pds[BSIZE];
    __shared__ int cur[BSIZE];
    __shared__ float sdv[BSIZE];
    int t = threadIdx.x, b = blockIdx.x;
    int node0 = b << BSHIFT;
    int e0 = bucket_off[b], e1 = bucket_off[b + 1];
    int n = e1 - e0;
    int pbase = (e0 + b * PADR2 + 7) & ~7;   // 8-aligned region start
    if (t < BSIZE) {
        cnt[t] = 0;
        int nd = node0 + t;
        sdv[t] = (nd < N_NODES) ? dinv[nd] : 0.f;
    }
    __syncthreads();
    for (int k = t; k < n; k += 256) {
        unsigned r = rec[e0 + k];
        stage[k] = r;
        atomicAdd(&cnt[r >> 20], 1);
    }
    __syncthreads();
    // inclusive scan of padded counts
    int pd = 0;
    if (t < BSIZE) { pd = (cnt[t] + 7) & ~7; pds[t] = pd; }
    __syncthreads();
    for (int off = 1; off < BSIZE; off <<= 1) {
        int v = (t < BSIZE && t >= off) ? pds[t - off] : 0;
        __syncthreads();
        if (t < BSIZE) pds[t] += v;
        __syncthreads();
    }
    if (t < BSIZE) {
        int startp = pbase + pds[t] - pd;
        cur[t] = startp;
        int nd = node0 + t;
        if (nd < N_NODES) row_meta[nd] = make_int2(startp, pd);
        for (int k = startp + cnt[t]; k < startp + pd; ++k)
            csr[k] = make_int2(0, 0);     // dummy: src=0, coef=0
    }
    __syncthreads();
    for (int k = t; k < n; k += 256) {
        unsigned r = stage[k];
        int dl = r >> 20;
        int s  = r & 0xFFFFF;
        int pos = atomicAdd(&cur[dl], 1);
        csr[pos] = make_int2(s, __float_as_int(dinv[s] * sdv[dl]));
    }
}

// ---------------------------------------------------------------------------
// GCN layer: gather aggregation, 8-edge chunks, csr as int4 (2 edges/load),
// fused W + bias + tanh + bf16x2 pack.
template <int FIN, bool PACKED>
__global__ __launch_bounds__(256) void layer_kernel(
        const void* __restrict__ h_in_v,
        const int2* __restrict__ row_meta,
        const int4* __restrict__ csr4,     // 2 edges per int4
        const float* __restrict__ dinv,
        const float* __restrict__ W,       // [FIN][32]
        const float* __restrict__ bias,    // [32]
        unsigned* __restrict__ h_out) {
    constexpr int STR = FIN + 1;
    __shared__ float sW[FIN * H_DIM];
    __shared__ float sb[H_DIM];
    __shared__ float agg[NPB][STR];
    int t = threadIdx.x;
    for (int k = t; k < FIN * H_DIM; k += 256) sW[k] = W[k];
    if (t < H_DIM) sb[t] = bias[t];

    int nl = t >> 4, ln = t & 15;
    int i = blockIdx.x * NPB + nl;
    int2 m = row_meta[i];
    float di = dinv[i], di2 = di * di;
    int p0i = m.x >> 1;                 // int4 index of row start (4-aligned)
    int p1i = (m.x + m.y) >> 1;

    if (PACKED) {
        const unsigned* hp = (const unsigned*)h_in_v;
        unsigned u = hp[i * 16 + ln];
        float acc0 = bf_lo(u) * di2, acc1 = bf_hi(u) * di2;
        for (int q = p0i; q < p1i; q += 4) {
            int4 a = csr4[q], b = csr4[q + 1], c = csr4[q + 2], d = csr4[q + 3];
            unsigned v0 = hp[a.x * 16 + ln], v1 = hp[a.z * 16 + ln];
            unsigned v2 = hp[b.x * 16 + ln], v3 = hp[b.z * 16 + ln];
            unsigned v4 = hp[c.x * 16 + ln], v5 = hp[c.z * 16 + ln];
            unsigned v6 = hp[d.x * 16 + ln], v7 = hp[d.z * 16 + ln];
            float c0 = __int_as_float(a.y), c1 = __int_as_float(a.w);
            float c2 = __int_as_float(b.y), c3 = __int_as_float(b.w);
            float c4 = __int_as_float(c.y), c5 = __int_as_float(c.w);
            float c6 = __int_as_float(d.y), c7 = __int_as_float(d.w);
            acc0 += bf_lo(v0) * c0 + bf_lo(v1) * c1 + bf_lo(v2) * c2 + bf_lo(v3) * c3
                  + bf_lo(v4) * c4 + bf_lo(v5) * c5 + bf_lo(v6) * c6 + bf_lo(v7) * c7;
            acc1 += bf_hi(v0) * c0 + bf_hi(v1) * c1 + bf_hi(v2) * c2 + bf_hi(v3) * c3
                  + bf_hi(v4) * c4 + bf_hi(v5) * c5 + bf_hi(v6) * c6 + bf_hi(v7) * c7;
        }
        agg[nl][2 * ln]     = acc0;
        agg[nl][2 * ln + 1] = acc1;
    } else {
        const float* xf = (const float*)h_in_v;
        float acc = xf[i * F_IN + ln] * di2;
        for (int q = p0i; q < p1i; q += 4) {
            int4 a = csr4[q], b = csr4[q + 1], c = csr4[q + 2], d = csr4[q + 3];
            float v0 = xf[a.x * F_IN + ln], v1 = xf[a.z * F_IN + ln];
            float v2 = xf[b.x * F_IN + ln], v3 = xf[b.z * F_IN + ln];
            float v4 = xf[c.x * F_IN + ln], v5 = xf[c.z * F_IN + ln];
            float v6 = xf[d.x * F_IN + ln], v7 = xf[d.z * F_IN + ln];
            acc += v0 * __int_as_float(a.y) + v1 * __int_as_float(a.w)
                 + v2 * __int_as_float(b.y) + v3 * __int_as_float(b.w)
                 + v4 * __int_as_float(c.y) + v5 * __int_as_float(c.w)
                 + v6 * __int_as_float(d.y) + v7 * __int_as_float(d.w);
        }
        agg[nl][ln] = acc;
    }
    __syncthreads();

    // transform + bias + tanh + pack  (16 nodes x 16 feat-pairs)
    int j0 = 2 * ln;
    float o0 = sb[j0], o1 = sb[j0 + 1];
    const float* arow = &agg[nl][0];
#pragma unroll
    for (int k = 0; k < FIN; ++k) {
        float a = arow[k];
        o0 += a * sW[k * H_DIM + j0];
        o1 += a * sW[k * H_DIM + j0 + 1];
    }
    h_out[i * 16 + ln] = pack_bf16x2(tanhf(o0), tanhf(o1));
}

// ---------------------------------------------------------------------------
// Per-graph pooling (batch sorted) + linear head, reading packed bf16 h.
__global__ __launch_bounds__(256) void pool_kernel(const unsigned* __restrict__ hp,
                                                   const int* __restrict__ batch,
                                                   const float* __restrict__ Wout,
                                                   const float* __restrict__ bout,
                                                   float* __restrict__ out) {
    int b = blockIdx.x;
    int t = threadIdx.x;
    int lane_n = t >> 5;
    int j = t & 31;

    int lo = 0, hi = N_NODES;
    while (lo < hi) { int mid = (lo + hi) >> 1; if (batch[mid] < b) lo = mid + 1; else hi = mid; }
    int start = lo;
    hi = N_NODES;
    while (lo < hi) { int mid = (lo + hi) >> 1; if (batch[mid] < b + 1) lo = mid + 1; else hi = mid; }
    int end = lo;

    float vmax = -INFINITY, vsum = 0.f;
    for (int i = start + lane_n; i < end; i += 8) {
        unsigned q = hp[i * 16 + (j >> 1)];
        float v = (j & 1) ? bf_hi(q) : bf_lo(q);
        vmax = fmaxf(vmax, v);
        vsum += v;
    }

    __shared__ float smax[8][32];
    __shared__ float ssum[8][32];
    __shared__ float pool96[96];
    smax[lane_n][j] = vmax;
    ssum[lane_n][j] = vsum;
    __syncthreads();

    if (t < 32) {
        float m = smax[0][t], s = ssum[0][t];
#pragma unroll
        for (int n = 1; n < 8; ++n) { m = fmaxf(m, smax[n][t]); s += ssum[n][t]; }
        int cnt = end - start;
        float mean = s / fmaxf((float)cnt, 1.0f);
        pool96[t]      = m;
        pool96[32 + t] = mean;
        pool96[64 + t] = s;
    }
    __syncthreads();

    if (t < 96) out[B_GRAPHS + b * 96 + t] = pool96[t];

    __shared__ float dotbuf[96];
    if (t < 96) dotbuf[t] = pool96[t] * Wout[t];
    __syncthreads();
    if (t == 0) {
        float acc = 0.f;
#pragma unroll
        for (int k = 0; k < 96; ++k) acc += dotbuf[k];
        out[b] = acc + bout[0];
    }
}

// ---------------------------------------------------------------------------
extern "C" void kernel_launch(void* const* d_in, const int* in_sizes, int n_in,
                              void* d_out, int out_size, void* d_ws, size_t ws_size,
                              hipStream_t stream) {
    const float* x     = (const float*)d_in[0];
    const int*   ei    = (const int*)  d_in[1];   // src = ei[0:E], dst = ei[E:2E]
    const int*   batch = (const int*)  d_in[2];
    const float* W0    = (const float*)d_in[3];
    const float* b0    = (const float*)d_in[4];
    const float* W1    = (const float*)d_in[5];
    const float* b1    = (const float*)d_in[6];
    const float* W2    = (const float*)d_in[7];
    const float* b2    = (const float*)d_in[8];
    const float* W3    = (const float*)d_in[9];
    const float* b3    = (const float*)d_in[10];
    const float* Wout  = (const float*)d_in[11];
    const float* bout  = (const float*)d_in[12];
    float* out = (float*)d_out;

    char* p = (char*)d_ws;
    float*    dinv       = (float*)p;    p += (size_t)N_NODES * 4;        // 16B-mult
    unsigned* hA         = (unsigned*)p; p += (size_t)N_NODES * 16 * 4;
    unsigned* rec        = (unsigned*)p; p += (size_t)N_EDGES * 4;        // reused as hB
    int2*     csr        = (int2*)p;     p += (size_t)TPAD * 8;
    int2*     row_meta   = (int2*)p;     p += (size_t)N_NODES * 8;
    int*      bucket_cnt = (int*)p;      p += NBUCKET * 4;
    int*      bucket_off = (int*)p;      p += (NBUCKET + 1) * 4;
    int*      bucket_cur = (int*)p;      p += NBUCKET * 4;
    unsigned* hB = rec;   // alias: rec dead once passC completes

    // ---- edge build: bucket partition -> per-bucket node sort -> padded CSR ----
    hipMemsetAsync(bucket_cnt, 0, NBUCKET * sizeof(int), stream);
    passA_kernel<<<NCHUNK, 256, 0, stream>>>(ei + N_EDGES, bucket_cnt);
    scan_kernel<<<1, 256, 0, stream>>>(bucket_cnt, bucket_off, bucket_cur);
    passB_kernel<<<NCHUNK, 256, 0, stream>>>(ei, bucket_cur, rec);
    dinv_kernel<<<NBUCKET, 256, 0, stream>>>(rec, bucket_off, dinv);
    passC_kernel<<<NBUCKET, 256, 0, stream>>>(rec, bucket_off, dinv,
                                              row_meta, csr, (const int*)nullptr);

    // ---- 4 GCN layers (gather, no atomics, int4 csr) ----
    layer_kernel<F_IN, false><<<LAYER_BLOCKS, 256, 0, stream>>>(
        x,  row_meta, (const int4*)csr, dinv, W0, b0, hA);
    layer_kernel<H_DIM, true><<<LAYER_BLOCKS, 256, 0, stream>>>(
        hA, row_meta, (const int4*)csr, dinv, W1, b1, hB);
    layer_kernel<H_DIM, true><<<LAYER_BLOCKS, 256, 0, stream>>>(
        hB, row_meta, (const int4*)csr, dinv, W2, b2, hA);
    layer_kernel<H_DIM, true><<<LAYER_BLOCKS, 256, 0, stream>>>(
        hA, row_meta, (const int4*)csr, dinv, W3, b3, hB);

    pool_kernel<<<B_GRAPHS, 256, 0, stream>>>(hB, batch, Wout, bout, out);
}

// Round 8
// 265.519 us; speedup vs baseline: 5.3989x; 1.0467x over previous
//
#include <hip/hip_runtime.h>
#include <math.h>

#define N_NODES 100000
#define N_EDGES 1600000
#define F_IN    16
#define H_DIM   32
#define B_GRAPHS 256

#define BSHIFT  7
#define BSIZE   128                                   // nodes per bucket
#define NBUCKET ((N_NODES + BSIZE - 1) / BSIZE)       // 782
#define EPB     8192                                  // edges per chunk block
#define NCHUNK  ((N_EDGES + EPB - 1) / EPB)           // 196
#define CAPB    2560                                  // fixed bucket stride (mean 2046, 11 sigma)
#define CSTRIDE 2944                                  // csr entries reserved per bucket (2560+384)
#define TPAD    (NBUCKET * CSTRIDE)
#define NPB     16                                    // nodes per layer block
#define LAYER_BLOCKS (N_NODES / NPB)                  // 6250

// ---------------------------------------------------------------------------
__device__ inline float bf_lo(unsigned u) { return __uint_as_float(u << 16); }
__device__ inline float bf_hi(unsigned u) { return __uint_as_float(u & 0xffff0000u); }
__device__ inline unsigned pack_bf16x2(float a, float b) {
    unsigned ua = __float_as_uint(a), ub = __float_as_uint(b);
    ua += 0x7fffu + ((ua >> 16) & 1u);    // RNE
    ub += 0x7fffu + ((ub >> 16) & 1u);
    return (ua >> 16) | (ub & 0xffff0000u);
}

// ---------------------------------------------------------------------------
// bucket_cur[b] = b * CAPB  (fixed-stride bucket layout; no histogram/scan)
__global__ __launch_bounds__(256) void init_cur_kernel(int* __restrict__ bucket_cur) {
    int b = blockIdx.x * 256 + threadIdx.x;
    if (b < NBUCKET) bucket_cur[b] = b * CAPB;
}

// Pass B: per-block histogram -> claim per-bucket runs -> direct scattered
// writes (run-contiguous => low writeback amp). Record = src | dst_local<<20.
__global__ __launch_bounds__(256) void passB_kernel(const int* __restrict__ ei,
                                                    int* __restrict__ bucket_cur,
                                                    unsigned* __restrict__ rec_out) {
    __shared__ int hist[NBUCKET];
    __shared__ int gcur[NBUCKET];
    int t = threadIdx.x;
    for (int k = t; k < NBUCKET; k += 256) hist[k] = 0;
    __syncthreads();

    const int* dst = ei + N_EDGES;
    int base = blockIdx.x * EPB;
    int end  = base + EPB; if (end > N_EDGES) end = N_EDGES;

    for (int e = base + t; e < end; e += 256) atomicAdd(&hist[dst[e] >> BSHIFT], 1);
    __syncthreads();

    for (int k = t; k < NBUCKET; k += 256) {
        int h = hist[k];
        gcur[k] = h ? atomicAdd(&bucket_cur[k], h) : 0;
    }
    __syncthreads();

    for (int e = base + t; e < end; e += 256) {
        int d = dst[e], s = ei[e];
        int bk = d >> BSHIFT;
        int pos = atomicAdd(&gcur[bk], 1);
        rec_out[pos] = (unsigned)s | ((unsigned)(d & (BSIZE - 1)) << 20);
    }
}

// Per-bucket in-degree -> dinv
__global__ __launch_bounds__(256) void dinv_kernel(const unsigned* __restrict__ rec,
                                                   const int* __restrict__ bucket_end,
                                                   float* __restrict__ dinv) {
    __shared__ int cnt[BSIZE];
    int t = threadIdx.x, b = blockIdx.x;
    if (t < BSIZE) cnt[t] = 0;
    __syncthreads();
    int e1 = bucket_end[b];
    for (int e = b * CAPB + t; e < e1; e += 256) atomicAdd(&cnt[rec[e] >> 20], 1);
    __syncthreads();
    int nd = (b << BSHIFT) + t;
    if (t < BSIZE && nd < N_NODES) dinv[nd] = rsqrtf((float)cnt[t] + 1.0f);
}

// Pass C: per-bucket node sort into padded interleaved CSR: entry=(src,coef).
// Rows padded to multiples of 4; dummy entries use the row's OWN node as src
// (coef=0) so pad gathers are spread (no hot line). row_meta=(start,padded_len).
__global__ __launch_bounds__(256) void passC_kernel(const unsigned* __restrict__ rec,
                                                    const int* __restrict__ bucket_end,
                                                    const float* __restrict__ dinv,
                                                    int2* __restrict__ row_meta,
                                                    int2* __restrict__ csr) {
    __shared__ unsigned stage[CAPB];
    __shared__ int cnt[BSIZE];
    __shared__ int pds[BSIZE];
    __shared__ int cur[BSIZE];
    __shared__ float sdv[BSIZE];
    int t = threadIdx.x, b = blockIdx.x;
    int node0 = b << BSHIFT;
    int e0 = b * CAPB;
    int n = bucket_end[b] - e0;
    int pbase = b * CSTRIDE;              // 8-aligned (CSTRIDE mult of 8... 2944%8==0)
    if (t < BSIZE) {
        cnt[t] = 0;
        int nd = node0 + t;
        sdv[t] = (nd < N_NODES) ? dinv[nd] : 0.f;
    }
    __syncthreads();
    for (int k = t; k < n; k += 256) {
        unsigned r = rec[e0 + k];
        stage[k] = r;
        atomicAdd(&cnt[r >> 20], 1);
    }
    __syncthreads();
    // inclusive scan of pad-4 counts
    int pd = 0;
    if (t < BSIZE) { pd = (cnt[t] + 3) & ~3; pds[t] = pd; }
    __syncthreads();
    for (int off = 1; off < BSIZE; off <<= 1) {
        int v = (t < BSIZE && t >= off) ? pds[t - off] : 0;
        __syncthreads();
        if (t < BSIZE) pds[t] += v;
        __syncthreads();
    }
    if (t < BSIZE) {
        int startp = pbase + pds[t] - pd;
        cur[t] = startp;
        int nd = node0 + t;
        if (nd < N_NODES) {
            row_meta[nd] = make_int2(startp, pd);
            // dummy pad: own node as src, coef 0 (spread, no hot line)
            for (int k = startp + cnt[t]; k < startp + pd; ++k)
                csr[k] = make_int2(nd, 0);
        }
    }
    __syncthreads();
    for (int k = t; k < n; k += 256) {
        unsigned r = stage[k];
        int dl = r >> 20;
        int s  = r & 0xFFFFF;
        int pos = atomicAdd(&cur[dl], 1);
        csr[pos] = make_int2(s, __float_as_int(dinv[s] * sdv[dl]));
    }
}

// ---------------------------------------------------------------------------
// GCN layer: gather aggregation, 8-edge main chunks + uniform 4-edge tail,
// csr as int4 (2 edges/load); fused W + bias + tanh + bf16x2 pack.
template <int FIN, bool PACKED>
__global__ __launch_bounds__(256) void layer_kernel(
        const void* __restrict__ h_in_v,
        const int2* __restrict__ row_meta,
        const int4* __restrict__ csr4,     // 2 edges per int4
        const float* __restrict__ dinv,
        const float* __restrict__ W,       // [FIN][32]
        const float* __restrict__ bias,    // [32]
        unsigned* __restrict__ h_out) {
    constexpr int STR = FIN + 1;
    __shared__ float sW[FIN * H_DIM];
    __shared__ float sb[H_DIM];
    __shared__ float agg[NPB][STR];
    int t = threadIdx.x;
    for (int k = t; k < FIN * H_DIM; k += 256) sW[k] = W[k];
    if (t < H_DIM) sb[t] = bias[t];

    int nl = t >> 4, ln = t & 15;
    int i = blockIdx.x * NPB + nl;
    int2 m = row_meta[i];
    float di = dinv[i], di2 = di * di;
    int q    = m.x >> 1;                // int4 index of row start (16B-aligned)
    int qend = (m.x + m.y) >> 1;

    if (PACKED) {
        const unsigned* hp = (const unsigned*)h_in_v;
        unsigned u = hp[i * 16 + ln];
        float acc0 = bf_lo(u) * di2, acc1 = bf_hi(u) * di2;
        for (; q + 4 <= qend; q += 4) {
            int4 a = csr4[q], b = csr4[q + 1], c = csr4[q + 2], d = csr4[q + 3];
            unsigned v0 = hp[a.x * 16 + ln], v1 = hp[a.z * 16 + ln];
            unsigned v2 = hp[b.x * 16 + ln], v3 = hp[b.z * 16 + ln];
            unsigned v4 = hp[c.x * 16 + ln], v5 = hp[c.z * 16 + ln];
            unsigned v6 = hp[d.x * 16 + ln], v7 = hp[d.z * 16 + ln];
            float c0 = __int_as_float(a.y), c1 = __int_as_float(a.w);
            float c2 = __int_as_float(b.y), c3 = __int_as_float(b.w);
            float c4 = __int_as_float(c.y), c5 = __int_as_float(c.w);
            float c6 = __int_as_float(d.y), c7 = __int_as_float(d.w);
            acc0 += bf_lo(v0) * c0 + bf_lo(v1) * c1 + bf_lo(v2) * c2 + bf_lo(v3) * c3
                  + bf_lo(v4) * c4 + bf_lo(v5) * c5 + bf_lo(v6) * c6 + bf_lo(v7) * c7;
            acc1 += bf_hi(v0) * c0 + bf_hi(v1) * c1 + bf_hi(v2) * c2 + bf_hi(v3) * c3
                  + bf_hi(v4) * c4 + bf_hi(v5) * c5 + bf_hi(v6) * c6 + bf_hi(v7) * c7;
        }
        if (q < qend) {                  // exactly 2 int4s (4 edges)
            int4 a = csr4[q], b = csr4[q + 1];
            unsigned v0 = hp[a.x * 16 + ln], v1 = hp[a.z * 16 + ln];
            unsigned v2 = hp[b.x * 16 + ln], v3 = hp[b.z * 16 + ln];
            float c0 = __int_as_float(a.y), c1 = __int_as_float(a.w);
            float c2 = __int_as_float(b.y), c3 = __int_as_float(b.w);
            acc0 += bf_lo(v0) * c0 + bf_lo(v1) * c1 + bf_lo(v2) * c2 + bf_lo(v3) * c3;
            acc1 += bf_hi(v0) * c0 + bf_hi(v1) * c1 + bf_hi(v2) * c2 + bf_hi(v3) * c3;
        }
        agg[nl][2 * ln]     = acc0;
        agg[nl][2 * ln + 1] = acc1;
    } else {
        const float* xf = (const float*)h_in_v;
        float acc = xf[i * F_IN + ln] * di2;
        for (; q + 4 <= qend; q += 4) {
            int4 a = csr4[q], b = csr4[q + 1], c = csr4[q + 2], d = csr4[q + 3];
            float v0 = xf[a.x * F_IN + ln], v1 = xf[a.z * F_IN + ln];
            float v2 = xf[b.x * F_IN + ln], v3 = xf[b.z * F_IN + ln];
            float v4 = xf[c.x * F_IN + ln], v5 = xf[c.z * F_IN + ln];
            float v6 = xf[d.x * F_IN + ln], v7 = xf[d.z * F_IN + ln];
            acc += v0 * __int_as_float(a.y) + v1 * __int_as_float(a.w)
                 + v2 * __int_as_float(b.y) + v3 * __int_as_float(b.w)
                 + v4 * __int_as_float(c.y) + v5 * __int_as_float(c.w)
                 + v6 * __int_as_float(d.y) + v7 * __int_as_float(d.w);
        }
        if (q < qend) {
            int4 a = csr4[q], b = csr4[q + 1];
            float v0 = xf[a.x * F_IN + ln], v1 = xf[a.z * F_IN + ln];
            float v2 = xf[b.x * F_IN + ln], v3 = xf[b.z * F_IN + ln];
            acc += v0 * __int_as_float(a.y) + v1 * __int_as_float(a.w)
                 + v2 * __int_as_float(b.y) + v3 * __int_as_float(b.w);
        }
        agg[nl][ln] = acc;
    }
    __syncthreads();

    // transform + bias + tanh + pack  (16 nodes x 16 feat-pairs)
    int j0 = 2 * ln;
    float o0 = sb[j0], o1 = sb[j0 + 1];
    const float* arow = &agg[nl][0];
#pragma unroll
    for (int k = 0; k < FIN; ++k) {
        float a = arow[k];
        o0 += a * sW[k * H_DIM + j0];
        o1 += a * sW[k * H_DIM + j0 + 1];
    }
    h_out[i * 16 + ln] = pack_bf16x2(tanhf(o0), tanhf(o1));
}

// ---------------------------------------------------------------------------
// Per-graph pooling (batch sorted) + linear head, reading packed bf16 h.
__global__ __launch_bounds__(256) void pool_kernel(const unsigned* __restrict__ hp,
                                                   const int* __restrict__ batch,
                                                   const float* __restrict__ Wout,
                                                   const float* __restrict__ bout,
                                                   float* __restrict__ out) {
    int b = blockIdx.x;
    int t = threadIdx.x;
    int lane_n = t >> 5;
    int j = t & 31;

    int lo = 0, hi = N_NODES;
    while (lo < hi) { int mid = (lo + hi) >> 1; if (batch[mid] < b) lo = mid + 1; else hi = mid; }
    int start = lo;
    hi = N_NODES;
    while (lo < hi) { int mid = (lo + hi) >> 1; if (batch[mid] < b + 1) lo = mid + 1; else hi = mid; }
    int end = lo;

    float vmax = -INFINITY, vsum = 0.f;
    for (int i = start + lane_n; i < end; i += 8) {
        unsigned q = hp[i * 16 + (j >> 1)];
        float v = (j & 1) ? bf_hi(q) : bf_lo(q);
        vmax = fmaxf(vmax, v);
        vsum += v;
    }

    __shared__ float smax[8][32];
    __shared__ float ssum[8][32];
    __shared__ float pool96[96];
    smax[lane_n][j] = vmax;
    ssum[lane_n][j] = vsum;
    __syncthreads();

    if (t < 32) {
        float m = smax[0][t], s = ssum[0][t];
#pragma unroll
        for (int n = 1; n < 8; ++n) { m = fmaxf(m, smax[n][t]); s += ssum[n][t]; }
        int cnt = end - start;
        float mean = s / fmaxf((float)cnt, 1.0f);
        pool96[t]      = m;
        pool96[32 + t] = mean;
        pool96[64 + t] = s;
    }
    __syncthreads();

    if (t < 96) out[B_GRAPHS + b * 96 + t] = pool96[t];

    __shared__ float dotbuf[96];
    if (t < 96) dotbuf[t] = pool96[t] * Wout[t];
    __syncthreads();
    if (t == 0) {
        float acc = 0.f;
#pragma unroll
        for (int k = 0; k < 96; ++k) acc += dotbuf[k];
        out[b] = acc + bout[0];
    }
}

// ---------------------------------------------------------------------------
extern "C" void kernel_launch(void* const* d_in, const int* in_sizes, int n_in,
                              void* d_out, int out_size, void* d_ws, size_t ws_size,
                              hipStream_t stream) {
    const float* x     = (const float*)d_in[0];
    const int*   ei    = (const int*)  d_in[1];   // src = ei[0:E], dst = ei[E:2E]
    const int*   batch = (const int*)  d_in[2];
    const float* W0    = (const float*)d_in[3];
    const float* b0    = (const float*)d_in[4];
    const float* W1    = (const float*)d_in[5];
    const float* b1    = (const float*)d_in[6];
    const float* W2    = (const float*)d_in[7];
    const float* b2    = (const float*)d_in[8];
    const float* W3    = (const float*)d_in[9];
    const float* b3    = (const float*)d_in[10];
    const float* Wout  = (const float*)d_in[11];
    const float* bout  = (const float*)d_in[12];
    float* out = (float*)d_out;

    char* p = (char*)d_ws;
    float*    dinv       = (float*)p;    p += (size_t)N_NODES * 4;            // 16B-mult
    unsigned* hA         = (unsigned*)p; p += (size_t)N_NODES * 16 * 4;
    unsigned* rec        = (unsigned*)p; p += (size_t)NBUCKET * CAPB * 4;     // 8 MB, reused as hB
    int2*     csr        = (int2*)p;     p += (size_t)TPAD * 8;               // 18.4 MB
    int2*     row_meta   = (int2*)p;     p += (size_t)N_NODES * 8;
    int*      bucket_cur = (int*)p;      p += NBUCKET * 4;
    unsigned* hB = rec;   // alias: rec dead once passC completes

    // ---- edge build: fixed-stride buckets -> per-bucket node sort -> CSR ----
    init_cur_kernel<<<(NBUCKET + 255) / 256, 256, 0, stream>>>(bucket_cur);
    passB_kernel<<<NCHUNK, 256, 0, stream>>>(ei, bucket_cur, rec);
    dinv_kernel<<<NBUCKET, 256, 0, stream>>>(rec, bucket_cur, dinv);
    passC_kernel<<<NBUCKET, 256, 0, stream>>>(rec, bucket_cur, dinv, row_meta, csr);

    // ---- 4 GCN layers (gather, no atomics, int4 csr) ----
    layer_kernel<F_IN, false><<<LAYER_BLOCKS, 256, 0, stream>>>(
        x,  row_meta, (const int4*)csr, dinv, W0, b0, hA);
    layer_kernel<H_DIM, true><<<LAYER_BLOCKS, 256, 0, stream>>>(
        hA, row_meta, (const int4*)csr, dinv, W1, b1, hB);
    layer_kernel<H_DIM, true><<<LAYER_BLOCKS, 256, 0, stream>>>(
        hB, row_meta, (const int4*)csr, dinv, W2, b2, hA);
    layer_kernel<H_DIM, true><<<LAYER_BLOCKS, 256, 0, stream>>>(
        hA, row_meta, (const int4*)csr, dinv, W3, b3, hB);

    pool_kernel<<<B_GRAPHS, 256, 0, stream>>>(hB, batch, Wout, bout, out);
}